// Round 3
// baseline (662.601 us; speedup 1.0000x reference)
//
#include <hip/hip_runtime.h>
#include <hip/hip_bf16.h>

#define NN 2048
#define FF 64
#define NH 8
#define BDIM 4
#define BH 32        // BDIM*NH

typedef __attribute__((ext_vector_type(8))) short short8;
typedef __attribute__((ext_vector_type(4))) float floatx4;
typedef __attribute__((ext_vector_type(4))) unsigned uint4v;
typedef __attribute__((ext_vector_type(2))) unsigned long long u64x2;

__device__ __forceinline__ float LDIN(const void* p, size_t i, int b16) {
    return b16 ? __bfloat162float(((const __hip_bfloat16*)p)[i]) : ((const float*)p)[i];
}
__device__ __forceinline__ unsigned packhi(float f0, float f1) {
    return __builtin_amdgcn_perm(__float_as_uint(f1), __float_as_uint(f0), 0x07060302);
}
__device__ __forceinline__ float hitrunc(float x) {
    return __uint_as_float(__float_as_uint(x) & 0xFFFF0000u);
}
// XOR-swizzled LDS index (stride 64 shorts, 8-short groups). col must be 4-aligned.
__device__ __forceinline__ int SWZ(int row, int col) {
    return row * 64 + ((((col >> 3) ^ (row & 7)) << 3) | (col & 7));
}
__device__ __forceinline__ float fast_tanh(float v) {
    float ex = __expf(2.0f * v);
    return 1.0f - 2.0f * __builtin_amdgcn_rcpf(ex + 1.0f);
}
__device__ __forceinline__ int sniff_b16(const void* h) {
    unsigned word = ((const unsigned*)h)[threadIdx.x & 63];
    unsigned lowexp = (word >> 7) & 0xFFu;
    bool plaus = (lowexp >= 96u && lowexp <= 159u);
    unsigned long long m = __ballot(plaus);
    return (__popcll(m) >= 48) ? 1 : 0;
}
// monotone float->unsigned map: f0 < f1  <=>  mkey(f0) < mkey(f1)
__device__ __forceinline__ unsigned mkey(float f) {
    unsigned u = __float_as_uint(f);
    return (u & 0x80000000u) ? ~u : (u | 0x80000000u);
}
__device__ __forceinline__ float unmkey(unsigned m) {
    unsigned u = (m & 0x80000000u) ? (m - 0x80000000u) : ~m;
    return __uint_as_float(u);
}

// per-bh flag barrier: 16 blocks of the same bh rendezvous.
// Release/acquire at agent scope handles cross-XCD L2 visibility (G16).
__device__ __forceinline__ void bhsync(int* f, int target) {
    __syncthreads();
    __threadfence();
    if (threadIdx.x == 0)
        __hip_atomic_fetch_add(f, 1, __ATOMIC_RELEASE, __HIP_MEMORY_SCOPE_AGENT);
    while (__hip_atomic_load(f, __ATOMIC_ACQUIRE, __HIP_MEMORY_SCOPE_AGENT) < target)
        __builtin_amdgcn_s_sleep(2);
    __syncthreads();
}

union SMu {
    struct { ushort aHi[4096]; ushort aLo[4096]; float sF[64 * 68]; } p;  // 33.4 KB
    struct { __align__(16) unsigned long long kp[2048]; int cnt2[256]; } r; // 17 KB
    struct { unsigned sdM[2048]; int cntS[128]; float rS[128]; } o;       // 9 KB
};

// ---- single persistent kernel: proj -> rank -> chunk -> emit -> out ---------
// grid 512 = 32 bh x 16 kb; 256 thr = 4 waves. All blocks co-resident
// (2 blocks/CU by __launch_bounds__(256,2), LDS 34KB), so per-bh flag
// spins cannot deadlock.
__global__ __launch_bounds__(256, 2) void k_mega(
    const void* __restrict__ h, const void* __restrict__ w,
    const void* __restrict__ asrc, const void* __restrict__ adst,
    const void* __restrict__ bias,
    int* __restrict__ flags,
    float* __restrict__ hpF, float* __restrict__ sArr,
    float* __restrict__ dArr, float* __restrict__ rArr,
    unsigned long long* __restrict__ SDJ,
    float* __restrict__ Teh, float* __restrict__ Tel,
    float* __restrict__ TehS, float* __restrict__ TelS,
    float* __restrict__ PreR, float* __restrict__ SufR,
    float* __restrict__ PreS, float* __restrict__ SufS,
    void* __restrict__ out)
{
    const int t = threadIdx.x;
    const int bh = blockIdx.x >> 4, kb = blockIdx.x & 15;
    const int b = bh >> 3, hd = bh & 7;
    const int lane = t & 63, wv = t >> 6;
    const int ml = lane & 15, q = lane >> 4;

    __shared__ SMu sm;
    __shared__ int sb16;
    if (t < 64) { int f = sniff_b16(h); if (t == 0) sb16 = f; }
    __syncthreads();
    const int b16 = sb16;

    // ---- w fragments direct to registers (w is L2-hot across all 512 blocks)
    short8 bhf[4][2], blf[4][2];
    if (b16) {
        const ushort* wp = (const ushort*)w + (size_t)hd * FF * FF;
#pragma unroll
        for (int nt = 0; nt < 4; ++nt)
#pragma unroll
            for (int kc = 0; kc < 2; ++kc) {
                ushort v[8];
#pragma unroll
                for (int j = 0; j < 8; ++j)
                    v[j] = wp[(kc * 32 + q * 8 + j) * FF + nt * 16 + ml];
                bhf[nt][kc] = *(short8*)v;
            }
    } else {
        const float* wp = (const float*)w + (size_t)hd * FF * FF;
#pragma unroll
        for (int nt = 0; nt < 4; ++nt)
#pragma unroll
            for (int kc = 0; kc < 2; ++kc) {
                float x[8];
#pragma unroll
                for (int j = 0; j < 8; ++j)
                    x[j] = wp[(kc * 32 + q * 8 + j) * FF + nt * 16 + ml];
                uint4v hv = { packhi(x[0], x[1]), packhi(x[2], x[3]),
                              packhi(x[4], x[5]), packhi(x[6], x[7]) };
                uint4v lv = { packhi(x[0] - hitrunc(x[0]), x[1] - hitrunc(x[1])),
                              packhi(x[2] - hitrunc(x[2]), x[3] - hitrunc(x[3])),
                              packhi(x[4] - hitrunc(x[4]), x[5] - hitrunc(x[5])),
                              packhi(x[6] - hitrunc(x[6]), x[7] - hitrunc(x[7])) };
                bhf[nt][kc] = __builtin_bit_cast(short8, hv);
                blf[nt][kc] = __builtin_bit_cast(short8, lv);
            }
    }

    float aS[4], aD[4];
#pragma unroll
    for (int nt = 0; nt < 4; ++nt) {
        aS[nt] = LDIN(asrc, hd * FF + nt * 16 + ml, b16);
        aD[nt] = LDIN(adst, hd * FF + nt * 16 + ml, b16);
    }

    // ================= P0: projection, two 64-row tiles ======================
#pragma unroll 1
    for (int e = 0; e < 2; ++e) {
        const int r0 = (kb * 2 + e) * 64;
        if (b16) {
            const ushort* hsrc = (const ushort*)h + (size_t)(b * NN + r0) * FF;
#pragma unroll
            for (int g0 = 0; g0 < 2; ++g0) {
                int g = t + g0 * 256;
                int row = g >> 3, c8 = (g & 7) * 8;
                uint4v u = *(const uint4v*)(hsrc + row * FF + c8);
                *(uint4v*)&sm.p.aHi[SWZ(row, c8)] = u;
            }
        } else {
            const float* hsrc = (const float*)h + (size_t)(b * NN + r0) * FF;
#pragma unroll
            for (int g0 = 0; g0 < 4; ++g0) {
                int g = t + g0 * 256;
                int row = g >> 4, c4 = (g & 15) * 4;
                floatx4 x = *(const floatx4*)(hsrc + row * FF + c4);
                uint2 hi2 = { packhi(x[0], x[1]), packhi(x[2], x[3]) };
                uint2 lo2 = { packhi(x[0] - hitrunc(x[0]), x[1] - hitrunc(x[1])),
                              packhi(x[2] - hitrunc(x[2]), x[3] - hitrunc(x[3])) };
                *(uint2*)&sm.p.aHi[SWZ(row, c4)] = hi2;
                *(uint2*)&sm.p.aLo[SWZ(row, c4)] = lo2;
            }
        }
        __syncthreads();

        short8 ah[2], al[2];
#pragma unroll
        for (int kc = 0; kc < 2; ++kc) {
            ah[kc] = *(const short8*)&sm.p.aHi[SWZ(wv * 16 + ml, kc * 32 + q * 8)];
            if (!b16) al[kc] = *(const short8*)&sm.p.aLo[SWZ(wv * 16 + ml, kc * 32 + q * 8)];
        }

        floatx4 acc[4];
#pragma unroll
        for (int nt = 0; nt < 4; ++nt) {
            floatx4 a = {0.f, 0.f, 0.f, 0.f};
            if (b16) {
#pragma unroll
                for (int kc = 0; kc < 2; ++kc)
                    a = __builtin_amdgcn_mfma_f32_16x16x32_bf16(ah[kc], bhf[nt][kc], a, 0, 0, 0);
            } else {
#pragma unroll
                for (int kc = 0; kc < 2; ++kc) {
                    a = __builtin_amdgcn_mfma_f32_16x16x32_bf16(ah[kc], bhf[nt][kc], a, 0, 0, 0);
                    a = __builtin_amdgcn_mfma_f32_16x16x32_bf16(ah[kc], blf[nt][kc], a, 0, 0, 0);
                    a = __builtin_amdgcn_mfma_f32_16x16x32_bf16(al[kc], bhf[nt][kc], a, 0, 0, 0);
                }
            }
            acc[nt] = a;
        }

#pragma unroll
        for (int nt = 0; nt < 4; ++nt)
#pragma unroll
            for (int reg = 0; reg < 4; ++reg)
                sm.p.sF[(wv * 16 + q * 4 + reg) * 68 + nt * 16 + ml] = acc[nt][reg];

        float ps[4] = {0.f, 0.f, 0.f, 0.f}, pd[4] = {0.f, 0.f, 0.f, 0.f};
#pragma unroll
        for (int nt = 0; nt < 4; ++nt)
#pragma unroll
            for (int reg = 0; reg < 4; ++reg) {
                float tv = fast_tanh(acc[nt][reg]);
                ps[reg] += tv * aS[nt];
                pd[reg] += tv * aD[nt];
            }
#pragma unroll
        for (int msk = 1; msk < 16; msk <<= 1)
#pragma unroll
            for (int reg = 0; reg < 4; ++reg) {
                ps[reg] += __shfl_xor(ps[reg], msk, 64);
                pd[reg] += __shfl_xor(pd[reg], msk, 64);
            }
        if (ml == 0) {
#pragma unroll
            for (int reg = 0; reg < 4; ++reg) {
                int i = bh * NN + r0 + wv * 16 + q * 4 + reg;
                float sv = ps[reg], dv = pd[reg];
                sArr[i] = sv;
                dArr[i] = dv;
                rArr[i] = __expf(-0.8f * sv);
            }
        }
        __syncthreads();
        {   // coalesced fp32 row write: each thread stores 16 floats of one row
            const int row = t >> 2, cs = (t & 3) * 16;
            const float* sp = &sm.p.sF[row * 68 + cs];
            float* dst = hpF + ((size_t)bh * NN + r0 + row) * 64 + cs;
            *(floatx4*)(dst)      = *(const floatx4*)(sp);
            *(floatx4*)(dst + 4)  = *(const floatx4*)(sp + 4);
            *(floatx4*)(dst + 8)  = *(const floatx4*)(sp + 8);
            *(floatx4*)(dst + 12) = *(const floatx4*)(sp + 12);
        }
        // next-iter staging writes aHi/aLo (disjoint from sF); all aHi reads of
        // this tile completed before the mid-barrier -> no extra barrier needed.
    }
    bhsync(&flags[0 * BH + bh], 16);

    // ================= P1: rank-by-count -> SDJ ==============================
    {
#pragma unroll
        for (int g = 0; g < 8; ++g) {
            int j = t + g * 256;
            unsigned m = mkey(dArr[bh * NN + j]);
            sm.r.kp[j] = ((unsigned long long)m << 32) | (unsigned)(2047 - j);
        }
        __syncthreads();
        const int jj = kb * 128 + (t & 127);
        const unsigned long long K = sm.r.kp[jj];
        const int cbase = (t >> 7) * 1024;
        int cnt = 0;
#pragma unroll 8
        for (int c = cbase; c < cbase + 1024; c += 4) {
            u64x2 a = *(const u64x2*)&sm.r.kp[c];
            u64x2 bb = *(const u64x2*)&sm.r.kp[c + 2];
            cnt += (a.x > K) + (a.y > K) + (bb.x > K) + (bb.y > K);
        }
        sm.r.cnt2[t] = cnt;
        __syncthreads();
        if (t < 128) {
            int cc = sm.r.cnt2[t] + sm.r.cnt2[t + 128];
            unsigned m = (unsigned)(K >> 32);
            SDJ[bh * NN + cc] = ((unsigned long long)m << 32) | (unsigned)jj;
        }
    }
    bhsync(&flags[1 * BH + bh], 16);

    // ================= P2: chunk totals (wave = one 32-rank chunk) ===========
    {
        const int c = kb * 4 + wv;
        float teh = 0.f, tel = 0.f, tehs = 0.f, tels = 0.f;
#pragma unroll 4
        for (int u = 0; u < 32; ++u) {
            unsigned long long K = SDJ[bh * NN + c * 32 + u];
            int jj = (int)(K & 0xFFFFFFFFu);
            float d = unmkey((unsigned)(K >> 32));
            float eh = __expf(d), el = __expf(0.2f * d);
            float hv = hpF[((size_t)bh * NN + jj) * 64 + lane];
            teh += eh * hv; tel += el * hv; tehs += eh; tels += el;
        }
        Teh[(bh * 64 + c) * 64 + lane] = teh;
        Tel[(bh * 64 + c) * 64 + lane] = tel;
        if (lane == 0) { TehS[bh * 64 + c] = tehs; TelS[bh * 64 + c] = tels; }
    }
    bhsync(&flags[2 * BH + bh], 16);

    // ========== P4: emit Pre/Suf tables (inline chunk-prefix, no cscan) ======
    {
        const int c = kb * 4 + wv;
        const size_t base = (size_t)bh * 2049;

        float run = 0.f, runs = 0.f;
        for (int cp = 0; cp < c; ++cp) {
            run  += Teh[(bh * 64 + cp) * 64 + lane];
            runs += TehS[bh * 64 + cp];
        }
#pragma unroll 4
        for (int u = 0; u < 32; ++u) {
            int x = c * 32 + u;
            unsigned long long K = SDJ[bh * NN + x];
            int jj = (int)(K & 0xFFFFFFFFu);
            float d = unmkey((unsigned)(K >> 32));
            PreR[(base + x) * 64 + lane] = run;
            if (lane == 0) PreS[base + x] = runs;
            float eh = __expf(d);
            float hv = hpF[((size_t)bh * NN + jj) * 64 + lane];
            run += eh * hv; runs += eh;
        }
        if (c == 63) {
            PreR[(base + 2048) * 64 + lane] = run;
            SufR[(base + 2048) * 64 + lane] = 0.f;
            if (lane == 0) { PreS[base + 2048] = runs; SufS[base + 2048] = 0.f; }
        }

        float runb = 0.f, runbs = 0.f;
        for (int cp = c + 1; cp < 64; ++cp) {
            runb  += Tel[(bh * 64 + cp) * 64 + lane];
            runbs += TelS[bh * 64 + cp];
        }
#pragma unroll 4
        for (int u = 31; u >= 0; --u) {
            int x = c * 32 + u;
            unsigned long long K = SDJ[bh * NN + x];
            int jj = (int)(K & 0xFFFFFFFFu);
            float d = unmkey((unsigned)(K >> 32));
            float el = __expf(0.2f * d);
            float hv = hpF[((size_t)bh * NN + jj) * 64 + lane];
            runb += el * hv; runbs += el;
            SufR[(base + x) * 64 + lane] = runb;
            if (lane == 0) SufS[base + x] = runbs;
        }
    }
    bhsync(&flags[3 * BH + bh], 16);

    // ================= P5: per-row search + blend + normalize ================
    {
#pragma unroll
        for (int g = 0; g < 8; ++g)
            sm.o.sdM[t + g * 256] = (unsigned)(SDJ[bh * NN + t + g * 256] >> 32);
        __syncthreads();
        const int i0 = kb * 128;
        if (t < 128) {   // cnt_i = #{ m_j >= m(thr_i) } over descending m array
            int i = i0 + t;
            unsigned mthr = mkey(-sArr[bh * NN + i]);
            int lo = 0, hi = 2048;
            while (lo < hi) {
                int m = (lo + hi) >> 1;
                if (sm.o.sdM[m] >= mthr) lo = m + 1; else hi = m;
            }
            sm.o.cntS[t] = lo;
            sm.o.rS[t] = rArr[bh * NN + i];
        }
        __syncthreads();
        const size_t base = (size_t)bh * 2049;
        float biasv = LDIN(bias, lane, b16);
#pragma unroll 4
        for (int u = 0; u < 32; ++u) {
            int iu = wv * 32 + u;
            int cnt = sm.o.cntS[iu];
            float rr = sm.o.rS[iu];
            size_t ro = (base + cnt) * 64 + lane;
            float val = (PreR[ro] + rr * SufR[ro])
                      / (PreS[base + cnt] + rr * SufS[base + cnt]) + biasv;
            size_t oi = ((size_t)bh * NN + i0 + iu) * 64 + lane;
            if (b16) ((__hip_bfloat16*)out)[oi] = __float2bfloat16(val);
            else     ((float*)out)[oi] = val;
        }
    }
}

extern "C" void kernel_launch(void* const* d_in, const int* in_sizes, int n_in,
                              void* d_out, int out_size, void* d_ws, size_t ws_size,
                              hipStream_t stream) {
    const void* h    = d_in[0];
    // d_in[1] = adj (bool) — unused by reference
    const void* w    = d_in[2];
    const void* asrc = d_in[3];
    const void* adst = d_in[4];
    const void* bias = d_in[5];

    float* ws = (float*)d_ws;
    int*    flags = (int*)ws;                             // 128 ints (4 phases x 32 bh)
    float*  hpF  = ws + 256;                              // 32*2048*64 fp32
    float*  sArr = hpF + (size_t)BH * NN * FF;            // 65536
    float*  dArr = sArr + BH * NN;
    float*  rArr = dArr + BH * NN;
    unsigned long long* SDJ = (unsigned long long*)(rArr + BH * NN); // 65536 u64
    float*  Teh  = (float*)(SDJ + (size_t)BH * NN);       // 32*64*64
    float*  Tel  = Teh + BH * 64 * 64;
    float*  TehS = Tel + BH * 64 * 64;                    // 32*64
    float*  TelS = TehS + BH * 64;
    float*  PreR = TelS + BH * 64;                        // 32*2049*64
    float*  SufR = PreR + (size_t)BH * 2049 * FF;
    float*  PreS = SufR + (size_t)BH * 2049 * FF;         // 32*2049
    float*  SufS = PreS + (size_t)BH * 2049;

    hipMemsetAsync(flags, 0, 512, stream);
    k_mega<<<BH * 16, 256, 0, stream>>>(h, w, asrc, adst, bias, flags,
                                        hpF, sArr, dArr, rArr, SDJ,
                                        Teh, Tel, TehS, TelS,
                                        PreR, SufR, PreS, SufS, d_out);
}

// Round 4
// 299.284 us; speedup vs baseline: 2.2140x; 2.2140x over previous
//
#include <hip/hip_runtime.h>
#include <hip/hip_bf16.h>

#define NN 2048
#define FF 64
#define NH 8
#define BDIM 4
#define BH 32        // BDIM*NH

typedef __attribute__((ext_vector_type(8))) short short8;
typedef __attribute__((ext_vector_type(4))) float floatx4;
typedef __attribute__((ext_vector_type(4))) unsigned uint4v;
typedef __attribute__((ext_vector_type(2))) unsigned long long u64x2;

__device__ __forceinline__ float LDIN(const void* p, size_t i, int b16) {
    return b16 ? __bfloat162float(((const __hip_bfloat16*)p)[i]) : ((const float*)p)[i];
}
__device__ __forceinline__ unsigned packhi(float f0, float f1) {
    return __builtin_amdgcn_perm(__float_as_uint(f1), __float_as_uint(f0), 0x07060302);
}
__device__ __forceinline__ float hitrunc(float x) {
    return __uint_as_float(__float_as_uint(x) & 0xFFFF0000u);
}
// XOR-swizzled LDS index (stride 64 shorts, 8-short groups). col must be 4-aligned.
__device__ __forceinline__ int SWZ(int row, int col) {
    return row * 64 + ((((col >> 3) ^ (row & 7)) << 3) | (col & 7));
}
__device__ __forceinline__ float fast_tanh(float v) {
    float ex = __expf(2.0f * v);
    return 1.0f - 2.0f * __builtin_amdgcn_rcpf(ex + 1.0f);
}
__device__ __forceinline__ int sniff_b16(const void* h) {
    unsigned word = ((const unsigned*)h)[threadIdx.x & 63];
    unsigned lowexp = (word >> 7) & 0xFFu;
    bool plaus = (lowexp >= 96u && lowexp <= 159u);
    unsigned long long m = __ballot(plaus);
    return (__popcll(m) >= 48) ? 1 : 0;
}
// monotone float->unsigned map: f0 < f1  <=>  mkey(f0) < mkey(f1)
__device__ __forceinline__ unsigned mkey(float f) {
    unsigned u = __float_as_uint(f);
    return (u & 0x80000000u) ? ~u : (u | 0x80000000u);
}
__device__ __forceinline__ float unmkey(unsigned m) {
    unsigned u = (m & 0x80000000u) ? (m - 0x80000000u) : ~m;
    return __uint_as_float(u);
}

// ---- per-bh rendezvous, poll-cheap edition ----------------------------------
// Each (phase,bh) has 16 one-writer slots (one 64B line). Writer kb stores a
// magic word (relaxed, agent) after a single release fence; wave 0 polls all
// 16 slots with RELAXED agent loads (no per-poll cache invalidate!) +
// s_sleep; after rendezvous every thread runs ONE acquire fence.
// Magic-slots need no zero-init -> no memset dispatch; workspace poison
// (byte-repeat patterns) cannot equal the non-repeating magic.
__device__ __forceinline__ void bhsync(unsigned* slots, int kb, unsigned magic) {
    __syncthreads();
    if (threadIdx.x == 0) {
        __builtin_amdgcn_fence(__ATOMIC_RELEASE, "agent");   // wb dirty L2 once
        __hip_atomic_store(&slots[kb], magic, __ATOMIC_RELAXED,
                           __HIP_MEMORY_SCOPE_AGENT);
    }
    if (threadIdx.x < 64) {
        for (;;) {
            unsigned v = (threadIdx.x < 16)
                ? __hip_atomic_load(&slots[threadIdx.x], __ATOMIC_RELAXED,
                                    __HIP_MEMORY_SCOPE_AGENT)
                : magic;
            if (__all(v == magic)) break;
            __builtin_amdgcn_s_sleep(8);
        }
    }
    __syncthreads();
    __builtin_amdgcn_fence(__ATOMIC_ACQUIRE, "agent");       // inv stale once
}

union SMu {
    struct { ushort aHi[4096]; ushort aLo[4096]; float sF[64 * 68]; } p;  // 33.4 KB
    struct { __align__(16) unsigned long long kp[2048]; int cnt2[256]; } r; // 17 KB
    struct { unsigned sdM[2048]; int cntS[128]; float rS[128]; } o;       // 9 KB
};

// ---- single persistent kernel: proj -> rank -> chunk -> emit -> out ---------
// grid 512; 256 thr = 4 waves. All blocks co-resident (2 blocks/CU via
// __launch_bounds__(256,2), LDS 34KB), so per-bh flag spins cannot deadlock.
// Block remap: all 16 blocks of a bh share blockIdx%8 -> same XCD under
// round-robin dispatch (L2 locality heuristic only).
__global__ __launch_bounds__(256, 2) void k_mega(
    const void* __restrict__ h, const void* __restrict__ w,
    const void* __restrict__ asrc, const void* __restrict__ adst,
    const void* __restrict__ bias,
    unsigned* __restrict__ flags,
    float* __restrict__ hpF, float* __restrict__ sArr,
    float* __restrict__ dArr, float* __restrict__ rArr,
    unsigned long long* __restrict__ SDJ,
    float* __restrict__ Teh, float* __restrict__ Tel,
    float* __restrict__ TehS, float* __restrict__ TelS,
    float* __restrict__ PreR, float* __restrict__ SufR,
    float* __restrict__ PreS, float* __restrict__ SufS,
    void* __restrict__ out)
{
    const int t = threadIdx.x;
    const int B = blockIdx.x;
    const int bh = (B & 7) * 4 + ((B >> 3) & 3);   // XCD-clustered mapping
    const int kb = B >> 5;
    const int b = bh >> 3, hd = bh & 7;
    const int lane = t & 63, wv = t >> 6;
    const int ml = lane & 15, q = lane >> 4;

    __shared__ SMu sm;
    __shared__ int sb16;
    if (t < 64) { int f = sniff_b16(h); if (t == 0) sb16 = f; }
    __syncthreads();
    const int b16 = sb16;

    // ---- w fragments direct to registers (w is L2-hot across all 512 blocks)
    short8 bhf[4][2], blf[4][2];
    if (b16) {
        const ushort* wp = (const ushort*)w + (size_t)hd * FF * FF;
#pragma unroll
        for (int nt = 0; nt < 4; ++nt)
#pragma unroll
            for (int kc = 0; kc < 2; ++kc) {
                ushort v[8];
#pragma unroll
                for (int j = 0; j < 8; ++j)
                    v[j] = wp[(kc * 32 + q * 8 + j) * FF + nt * 16 + ml];
                bhf[nt][kc] = *(short8*)v;
            }
    } else {
        const float* wp = (const float*)w + (size_t)hd * FF * FF;
#pragma unroll
        for (int nt = 0; nt < 4; ++nt)
#pragma unroll
            for (int kc = 0; kc < 2; ++kc) {
                float x[8];
#pragma unroll
                for (int j = 0; j < 8; ++j)
                    x[j] = wp[(kc * 32 + q * 8 + j) * FF + nt * 16 + ml];
                uint4v hv = { packhi(x[0], x[1]), packhi(x[2], x[3]),
                              packhi(x[4], x[5]), packhi(x[6], x[7]) };
                uint4v lv = { packhi(x[0] - hitrunc(x[0]), x[1] - hitrunc(x[1])),
                              packhi(x[2] - hitrunc(x[2]), x[3] - hitrunc(x[3])),
                              packhi(x[4] - hitrunc(x[4]), x[5] - hitrunc(x[5])),
                              packhi(x[6] - hitrunc(x[6]), x[7] - hitrunc(x[7])) };
                bhf[nt][kc] = __builtin_bit_cast(short8, hv);
                blf[nt][kc] = __builtin_bit_cast(short8, lv);
            }
    }

    float aS[4], aD[4];
#pragma unroll
    for (int nt = 0; nt < 4; ++nt) {
        aS[nt] = LDIN(asrc, hd * FF + nt * 16 + ml, b16);
        aD[nt] = LDIN(adst, hd * FF + nt * 16 + ml, b16);
    }

    // ================= P0: projection, two 64-row tiles ======================
#pragma unroll 1
    for (int e = 0; e < 2; ++e) {
        const int r0 = (kb * 2 + e) * 64;
        if (b16) {
            const ushort* hsrc = (const ushort*)h + (size_t)(b * NN + r0) * FF;
#pragma unroll
            for (int g0 = 0; g0 < 2; ++g0) {
                int g = t + g0 * 256;
                int row = g >> 3, c8 = (g & 7) * 8;
                uint4v u = *(const uint4v*)(hsrc + row * FF + c8);
                *(uint4v*)&sm.p.aHi[SWZ(row, c8)] = u;
            }
        } else {
            const float* hsrc = (const float*)h + (size_t)(b * NN + r0) * FF;
#pragma unroll
            for (int g0 = 0; g0 < 4; ++g0) {
                int g = t + g0 * 256;
                int row = g >> 4, c4 = (g & 15) * 4;
                floatx4 x = *(const floatx4*)(hsrc + row * FF + c4);
                uint2 hi2 = { packhi(x[0], x[1]), packhi(x[2], x[3]) };
                uint2 lo2 = { packhi(x[0] - hitrunc(x[0]), x[1] - hitrunc(x[1])),
                              packhi(x[2] - hitrunc(x[2]), x[3] - hitrunc(x[3])) };
                *(uint2*)&sm.p.aHi[SWZ(row, c4)] = hi2;
                *(uint2*)&sm.p.aLo[SWZ(row, c4)] = lo2;
            }
        }
        __syncthreads();

        short8 ah[2], al[2];
#pragma unroll
        for (int kc = 0; kc < 2; ++kc) {
            ah[kc] = *(const short8*)&sm.p.aHi[SWZ(wv * 16 + ml, kc * 32 + q * 8)];
            if (!b16) al[kc] = *(const short8*)&sm.p.aLo[SWZ(wv * 16 + ml, kc * 32 + q * 8)];
        }

        floatx4 acc[4];
#pragma unroll
        for (int nt = 0; nt < 4; ++nt) {
            floatx4 a = {0.f, 0.f, 0.f, 0.f};
            if (b16) {
#pragma unroll
                for (int kc = 0; kc < 2; ++kc)
                    a = __builtin_amdgcn_mfma_f32_16x16x32_bf16(ah[kc], bhf[nt][kc], a, 0, 0, 0);
            } else {
#pragma unroll
                for (int kc = 0; kc < 2; ++kc) {
                    a = __builtin_amdgcn_mfma_f32_16x16x32_bf16(ah[kc], bhf[nt][kc], a, 0, 0, 0);
                    a = __builtin_amdgcn_mfma_f32_16x16x32_bf16(ah[kc], blf[nt][kc], a, 0, 0, 0);
                    a = __builtin_amdgcn_mfma_f32_16x16x32_bf16(al[kc], bhf[nt][kc], a, 0, 0, 0);
                }
            }
            acc[nt] = a;
        }

#pragma unroll
        for (int nt = 0; nt < 4; ++nt)
#pragma unroll
            for (int reg = 0; reg < 4; ++reg)
                sm.p.sF[(wv * 16 + q * 4 + reg) * 68 + nt * 16 + ml] = acc[nt][reg];

        float ps[4] = {0.f, 0.f, 0.f, 0.f}, pd[4] = {0.f, 0.f, 0.f, 0.f};
#pragma unroll
        for (int nt = 0; nt < 4; ++nt)
#pragma unroll
            for (int reg = 0; reg < 4; ++reg) {
                float tv = fast_tanh(acc[nt][reg]);
                ps[reg] += tv * aS[nt];
                pd[reg] += tv * aD[nt];
            }
#pragma unroll
        for (int msk = 1; msk < 16; msk <<= 1)
#pragma unroll
            for (int reg = 0; reg < 4; ++reg) {
                ps[reg] += __shfl_xor(ps[reg], msk, 64);
                pd[reg] += __shfl_xor(pd[reg], msk, 64);
            }
        if (ml == 0) {
#pragma unroll
            for (int reg = 0; reg < 4; ++reg) {
                int i = bh * NN + r0 + wv * 16 + q * 4 + reg;
                float sv = ps[reg], dv = pd[reg];
                sArr[i] = sv;
                dArr[i] = dv;
                rArr[i] = __expf(-0.8f * sv);
            }
        }
        __syncthreads();
        {   // coalesced fp32 row write: each thread stores 16 floats of one row
            const int row = t >> 2, cs = (t & 3) * 16;
            const float* sp = &sm.p.sF[row * 68 + cs];
            float* dst = hpF + ((size_t)bh * NN + r0 + row) * 64 + cs;
            *(floatx4*)(dst)      = *(const floatx4*)(sp);
            *(floatx4*)(dst + 4)  = *(const floatx4*)(sp + 4);
            *(floatx4*)(dst + 8)  = *(const floatx4*)(sp + 8);
            *(floatx4*)(dst + 12) = *(const floatx4*)(sp + 12);
        }
        // next-iter staging writes aHi/aLo (disjoint from sF); all aHi reads of
        // this tile completed before the mid-barrier -> no extra barrier needed.
    }
    bhsync(&flags[(0 * BH + bh) * 16], kb, 0x3A7C9E51u);

    // ================= P1: rank-by-count -> SDJ ==============================
    {
#pragma unroll
        for (int g = 0; g < 8; ++g) {
            int j = t + g * 256;
            unsigned m = mkey(dArr[bh * NN + j]);
            sm.r.kp[j] = ((unsigned long long)m << 32) | (unsigned)(2047 - j);
        }
        __syncthreads();
        const int jj = kb * 128 + (t & 127);
        const unsigned long long K = sm.r.kp[jj];
        const int cbase = (t >> 7) * 1024;
        int cnt = 0;
#pragma unroll 8
        for (int c = cbase; c < cbase + 1024; c += 4) {
            u64x2 a = *(const u64x2*)&sm.r.kp[c];
            u64x2 bb = *(const u64x2*)&sm.r.kp[c + 2];
            cnt += (a.x > K) + (a.y > K) + (bb.x > K) + (bb.y > K);
        }
        sm.r.cnt2[t] = cnt;
        __syncthreads();
        if (t < 128) {
            int cc = sm.r.cnt2[t] + sm.r.cnt2[t + 128];
            unsigned m = (unsigned)(K >> 32);
            SDJ[bh * NN + cc] = ((unsigned long long)m << 32) | (unsigned)jj;
        }
    }
    bhsync(&flags[(1 * BH + bh) * 16], kb, 0x3A7C9E52u);

    // ================= P2: chunk totals (wave = one 32-rank chunk) ===========
    {
        const int c = kb * 4 + wv;
        float teh = 0.f, tel = 0.f, tehs = 0.f, tels = 0.f;
#pragma unroll 4
        for (int u = 0; u < 32; ++u) {
            unsigned long long K = SDJ[bh * NN + c * 32 + u];
            int jj = (int)(K & 0xFFFFFFFFu);
            float d = unmkey((unsigned)(K >> 32));
            float eh = __expf(d), el = __expf(0.2f * d);
            float hv = hpF[((size_t)bh * NN + jj) * 64 + lane];
            teh += eh * hv; tel += el * hv; tehs += eh; tels += el;
        }
        Teh[(bh * 64 + c) * 64 + lane] = teh;
        Tel[(bh * 64 + c) * 64 + lane] = tel;
        if (lane == 0) { TehS[bh * 64 + c] = tehs; TelS[bh * 64 + c] = tels; }
    }
    bhsync(&flags[(2 * BH + bh) * 16], kb, 0x3A7C9E53u);

    // ========== P4: emit Pre/Suf tables (inline chunk-prefix, no cscan) ======
    {
        const int c = kb * 4 + wv;
        const size_t base = (size_t)bh * 2049;

        float run = 0.f, runs = 0.f;
        for (int cp = 0; cp < c; ++cp) {
            run  += Teh[(bh * 64 + cp) * 64 + lane];
            runs += TehS[bh * 64 + cp];
        }
#pragma unroll 4
        for (int u = 0; u < 32; ++u) {
            int x = c * 32 + u;
            unsigned long long K = SDJ[bh * NN + x];
            int jj = (int)(K & 0xFFFFFFFFu);
            float d = unmkey((unsigned)(K >> 32));
            PreR[(base + x) * 64 + lane] = run;
            if (lane == 0) PreS[base + x] = runs;
            float eh = __expf(d);
            float hv = hpF[((size_t)bh * NN + jj) * 64 + lane];
            run += eh * hv; runs += eh;
        }
        if (c == 63) {
            PreR[(base + 2048) * 64 + lane] = run;
            SufR[(base + 2048) * 64 + lane] = 0.f;
            if (lane == 0) { PreS[base + 2048] = runs; SufS[base + 2048] = 0.f; }
        }

        float runb = 0.f, runbs = 0.f;
        for (int cp = c + 1; cp < 64; ++cp) {
            runb  += Tel[(bh * 64 + cp) * 64 + lane];
            runbs += TelS[bh * 64 + cp];
        }
#pragma unroll 4
        for (int u = 31; u >= 0; --u) {
            int x = c * 32 + u;
            unsigned long long K = SDJ[bh * NN + x];
            int jj = (int)(K & 0xFFFFFFFFu);
            float d = unmkey((unsigned)(K >> 32));
            float el = __expf(0.2f * d);
            float hv = hpF[((size_t)bh * NN + jj) * 64 + lane];
            runb += el * hv; runbs += el;
            SufR[(base + x) * 64 + lane] = runb;
            if (lane == 0) SufS[base + x] = runbs;
        }
    }
    bhsync(&flags[(3 * BH + bh) * 16], kb, 0x3A7C9E54u);

    // ================= P5: per-row search + blend + normalize ================
    {
#pragma unroll
        for (int g = 0; g < 8; ++g)
            sm.o.sdM[t + g * 256] = (unsigned)(SDJ[bh * NN + t + g * 256] >> 32);
        __syncthreads();
        const int i0 = kb * 128;
        if (t < 128) {   // cnt_i = #{ m_j >= m(thr_i) } over descending m array
            int i = i0 + t;
            unsigned mthr = mkey(-sArr[bh * NN + i]);
            int lo = 0, hi = 2048;
            while (lo < hi) {
                int m = (lo + hi) >> 1;
                if (sm.o.sdM[m] >= mthr) lo = m + 1; else hi = m;
            }
            sm.o.cntS[t] = lo;
            sm.o.rS[t] = rArr[bh * NN + i];
        }
        __syncthreads();
        const size_t base = (size_t)bh * 2049;
        float biasv = LDIN(bias, lane, b16);
#pragma unroll 4
        for (int u = 0; u < 32; ++u) {
            int iu = wv * 32 + u;
            int cnt = sm.o.cntS[iu];
            float rr = sm.o.rS[iu];
            size_t ro = (base + cnt) * 64 + lane;
            float val = (PreR[ro] + rr * SufR[ro])
                      / (PreS[base + cnt] + rr * SufS[base + cnt]) + biasv;
            size_t oi = ((size_t)bh * NN + i0 + iu) * 64 + lane;
            if (b16) ((__hip_bfloat16*)out)[oi] = __float2bfloat16(val);
            else     ((float*)out)[oi] = val;
        }
    }
}

extern "C" void kernel_launch(void* const* d_in, const int* in_sizes, int n_in,
                              void* d_out, int out_size, void* d_ws, size_t ws_size,
                              hipStream_t stream) {
    const void* h    = d_in[0];
    // d_in[1] = adj (bool) — unused by reference
    const void* w    = d_in[2];
    const void* asrc = d_in[3];
    const void* adst = d_in[4];
    const void* bias = d_in[5];

    float* ws = (float*)d_ws;
    unsigned* flags = (unsigned*)ws;                      // 4 phases x 32 bh x 16 slots
    float*  hpF  = ws + 4096;                             // 32*2048*64 fp32
    float*  sArr = hpF + (size_t)BH * NN * FF;            // 65536
    float*  dArr = sArr + BH * NN;
    float*  rArr = dArr + BH * NN;
    unsigned long long* SDJ = (unsigned long long*)(rArr + BH * NN); // 65536 u64
    float*  Teh  = (float*)(SDJ + (size_t)BH * NN);       // 32*64*64
    float*  Tel  = Teh + BH * 64 * 64;
    float*  TehS = Tel + BH * 64 * 64;                    // 32*64
    float*  TelS = TehS + BH * 64;
    float*  PreR = TelS + BH * 64;                        // 32*2049*64
    float*  SufR = PreR + (size_t)BH * 2049 * FF;
    float*  PreS = SufR + (size_t)BH * 2049 * FF;         // 32*2049
    float*  SufS = PreS + (size_t)BH * 2049;

    k_mega<<<BH * 16, 256, 0, stream>>>(h, w, asrc, adst, bias, flags,
                                        hpF, sArr, dArr, rArr, SDJ,
                                        Teh, Tel, TehS, TelS,
                                        PreR, SufR, PreS, SufS, d_out);
}

// Round 5
// 262.516 us; speedup vs baseline: 2.5240x; 1.1401x over previous
//
#include <hip/hip_runtime.h>
#include <hip/hip_bf16.h>

#define NN 2048
#define FF 64
#define NH 8
#define BDIM 4
#define BH 32        // BDIM*NH

typedef __attribute__((ext_vector_type(8))) short short8;
typedef __attribute__((ext_vector_type(4))) float floatx4;
typedef __attribute__((ext_vector_type(4))) unsigned uint4v;
typedef __attribute__((ext_vector_type(2))) unsigned long long u64x2;

__device__ __forceinline__ float LDIN(const void* p, size_t i, int b16) {
    return b16 ? __bfloat162float(((const __hip_bfloat16*)p)[i]) : ((const float*)p)[i];
}
__device__ __forceinline__ unsigned packhi(float f0, float f1) {
    return __builtin_amdgcn_perm(__float_as_uint(f1), __float_as_uint(f0), 0x07060302);
}
__device__ __forceinline__ float hitrunc(float x) {
    return __uint_as_float(__float_as_uint(x) & 0xFFFF0000u);
}
// XOR-swizzled LDS index (stride 64 shorts, 8-short groups). col must be 4-aligned.
__device__ __forceinline__ int SWZ(int row, int col) {
    return row * 64 + ((((col >> 3) ^ (row & 7)) << 3) | (col & 7));
}
__device__ __forceinline__ float fast_tanh(float v) {
    float ex = __expf(2.0f * v);
    return 1.0f - 2.0f * __builtin_amdgcn_rcpf(ex + 1.0f);
}
__device__ __forceinline__ int sniff_b16(const void* h) {
    unsigned word = ((const unsigned*)h)[threadIdx.x & 63];
    unsigned lowexp = (word >> 7) & 0xFFu;
    bool plaus = (lowexp >= 96u && lowexp <= 159u);
    unsigned long long m = __ballot(plaus);
    return (__popcll(m) >= 48) ? 1 : 0;
}
// monotone float->unsigned map: f0 < f1  <=>  mkey(f0) < mkey(f1)
__device__ __forceinline__ unsigned mkey(float f) {
    unsigned u = __float_as_uint(f);
    return (u & 0x80000000u) ? ~u : (u | 0x80000000u);
}
__device__ __forceinline__ float unmkey(unsigned m) {
    unsigned u = (m & 0x80000000u) ? (m - 0x80000000u) : ~m;
    return __uint_as_float(u);
}

// ---- agent-coherent (IF$-routed) scalar access helpers ----------------------
// Relaxed agent-scope atomics compile to sc-flagged global ops that bypass the
// non-coherent per-XCD L2 -> per-location agent coherence with NO cache-wide
// fence ops. All cross-block data flows through these.
__device__ __forceinline__ void stF(float* p, float v) {
    __hip_atomic_store(p, v, __ATOMIC_RELAXED, __HIP_MEMORY_SCOPE_AGENT);
}
__device__ __forceinline__ float ldF(const float* p) {
    return __hip_atomic_load(p, __ATOMIC_RELAXED, __HIP_MEMORY_SCOPE_AGENT);
}
__device__ __forceinline__ void stU64(unsigned long long* p, unsigned long long v) {
    __hip_atomic_store(p, v, __ATOMIC_RELAXED, __HIP_MEMORY_SCOPE_AGENT);
}
__device__ __forceinline__ unsigned long long ldU64(const unsigned long long* p) {
    return __hip_atomic_load(p, __ATOMIC_RELAXED, __HIP_MEMORY_SCOPE_AGENT);
}
__device__ __forceinline__ void stF2(float* p, float a, float b) {
    float2 f2; f2.x = a; f2.y = b;
    stU64((unsigned long long*)p, __builtin_bit_cast(unsigned long long, f2));
}

// ---- per-bh rendezvous: NO cache-maintenance fences -------------------------
// __syncthreads() drains vmcnt(0) (compiler emits full s_waitcnt before
// s_barrier), so all prior sc-flagged stores have reached the IF$ before the
// flag store. Readers pull data through sc-flagged loads, so no acquire
// invalidate is needed either. Magic slots: no zero-init required; workspace
// poison (byte-repeat) cannot equal the non-repeating magic.
__device__ __forceinline__ void bhsync(unsigned* slots, int kb, unsigned magic) {
    asm volatile("s_waitcnt vmcnt(0)" ::: "memory");
    __syncthreads();
    if (threadIdx.x == 0)
        __hip_atomic_store(&slots[kb], magic, __ATOMIC_RELAXED,
                           __HIP_MEMORY_SCOPE_AGENT);
    if (threadIdx.x < 64) {
        for (;;) {
            unsigned v = (threadIdx.x < 16)
                ? __hip_atomic_load(&slots[threadIdx.x], __ATOMIC_RELAXED,
                                    __HIP_MEMORY_SCOPE_AGENT)
                : magic;
            if (__all(v == magic)) break;
            __builtin_amdgcn_s_sleep(2);
        }
    }
    __syncthreads();
}

union SMu {
    struct { ushort aHi[4096]; ushort aLo[4096]; float sF[64 * 68]; } p;  // 33.4 KB
    struct { __align__(16) unsigned long long kp[2048]; int cnt2[256]; } r; // 17 KB
    struct { unsigned sdM[2048]; int cntS[128]; float rS[128]; } o;       // 9 KB
};

// ---- single persistent kernel: proj -> rank -> chunk -> emit -> out ---------
// grid 512; 256 thr = 4 waves. Cooperative launch gang-schedules all blocks
// (2/CU); per-bh flag sync; all cross-block data via IF$-routed accesses.
__global__ __launch_bounds__(256, 2) void k_mega(
    const void* __restrict__ h, const void* __restrict__ w,
    const void* __restrict__ asrc, const void* __restrict__ adst,
    const void* __restrict__ bias,
    unsigned* __restrict__ flags,
    float* __restrict__ hpF, float* __restrict__ sArr,
    float* __restrict__ dArr, float* __restrict__ rArr,
    unsigned long long* __restrict__ SDJ,
    float* __restrict__ Teh, float* __restrict__ Tel,
    float* __restrict__ TehS, float* __restrict__ TelS,
    float* __restrict__ PreR, float* __restrict__ SufR,
    float* __restrict__ PreS, float* __restrict__ SufS,
    void* __restrict__ out)
{
    const int t = threadIdx.x;
    const int B = blockIdx.x;
    const int bh = (B & 7) * 4 + ((B >> 3) & 3);   // XCD-clustered mapping
    const int kb = B >> 5;
    const int b = bh >> 3, hd = bh & 7;
    const int lane = t & 63, wv = t >> 6;
    const int ml = lane & 15, q = lane >> 4;

    __shared__ SMu sm;
    __shared__ int sb16;
    if (t < 64) { int f = sniff_b16(h); if (t == 0) sb16 = f; }
    __syncthreads();
    const int b16 = sb16;

    // ---- w fragments direct to registers (w is L2-hot across all 512 blocks)
    short8 bhf[4][2], blf[4][2];
    if (b16) {
        const ushort* wp = (const ushort*)w + (size_t)hd * FF * FF;
#pragma unroll
        for (int nt = 0; nt < 4; ++nt)
#pragma unroll
            for (int kc = 0; kc < 2; ++kc) {
                ushort v[8];
#pragma unroll
                for (int j = 0; j < 8; ++j)
                    v[j] = wp[(kc * 32 + q * 8 + j) * FF + nt * 16 + ml];
                bhf[nt][kc] = *(short8*)v;
            }
    } else {
        const float* wp = (const float*)w + (size_t)hd * FF * FF;
#pragma unroll
        for (int nt = 0; nt < 4; ++nt)
#pragma unroll
            for (int kc = 0; kc < 2; ++kc) {
                float x[8];
#pragma unroll
                for (int j = 0; j < 8; ++j)
                    x[j] = wp[(kc * 32 + q * 8 + j) * FF + nt * 16 + ml];
                uint4v hv = { packhi(x[0], x[1]), packhi(x[2], x[3]),
                              packhi(x[4], x[5]), packhi(x[6], x[7]) };
                uint4v lv = { packhi(x[0] - hitrunc(x[0]), x[1] - hitrunc(x[1])),
                              packhi(x[2] - hitrunc(x[2]), x[3] - hitrunc(x[3])),
                              packhi(x[4] - hitrunc(x[4]), x[5] - hitrunc(x[5])),
                              packhi(x[6] - hitrunc(x[6]), x[7] - hitrunc(x[7])) };
                bhf[nt][kc] = __builtin_bit_cast(short8, hv);
                blf[nt][kc] = __builtin_bit_cast(short8, lv);
            }
    }

    float aS[4], aD[4];
#pragma unroll
    for (int nt = 0; nt < 4; ++nt) {
        aS[nt] = LDIN(asrc, hd * FF + nt * 16 + ml, b16);
        aD[nt] = LDIN(adst, hd * FF + nt * 16 + ml, b16);
    }

    // ================= P0: projection, two 64-row tiles ======================
#pragma unroll 1
    for (int e = 0; e < 2; ++e) {
        const int r0 = (kb * 2 + e) * 64;
        if (b16) {
            const ushort* hsrc = (const ushort*)h + (size_t)(b * NN + r0) * FF;
#pragma unroll
            for (int g0 = 0; g0 < 2; ++g0) {
                int g = t + g0 * 256;
                int row = g >> 3, c8 = (g & 7) * 8;
                uint4v u = *(const uint4v*)(hsrc + row * FF + c8);
                *(uint4v*)&sm.p.aHi[SWZ(row, c8)] = u;
            }
        } else {
            const float* hsrc = (const float*)h + (size_t)(b * NN + r0) * FF;
#pragma unroll
            for (int g0 = 0; g0 < 4; ++g0) {
                int g = t + g0 * 256;
                int row = g >> 4, c4 = (g & 15) * 4;
                floatx4 x = *(const floatx4*)(hsrc + row * FF + c4);
                uint2 hi2 = { packhi(x[0], x[1]), packhi(x[2], x[3]) };
                uint2 lo2 = { packhi(x[0] - hitrunc(x[0]), x[1] - hitrunc(x[1])),
                              packhi(x[2] - hitrunc(x[2]), x[3] - hitrunc(x[3])) };
                *(uint2*)&sm.p.aHi[SWZ(row, c4)] = hi2;
                *(uint2*)&sm.p.aLo[SWZ(row, c4)] = lo2;
            }
        }
        __syncthreads();

        short8 ah[2], al[2];
#pragma unroll
        for (int kc = 0; kc < 2; ++kc) {
            ah[kc] = *(const short8*)&sm.p.aHi[SWZ(wv * 16 + ml, kc * 32 + q * 8)];
            if (!b16) al[kc] = *(const short8*)&sm.p.aLo[SWZ(wv * 16 + ml, kc * 32 + q * 8)];
        }

        floatx4 acc[4];
#pragma unroll
        for (int nt = 0; nt < 4; ++nt) {
            floatx4 a = {0.f, 0.f, 0.f, 0.f};
            if (b16) {
#pragma unroll
                for (int kc = 0; kc < 2; ++kc)
                    a = __builtin_amdgcn_mfma_f32_16x16x32_bf16(ah[kc], bhf[nt][kc], a, 0, 0, 0);
            } else {
#pragma unroll
                for (int kc = 0; kc < 2; ++kc) {
                    a = __builtin_amdgcn_mfma_f32_16x16x32_bf16(ah[kc], bhf[nt][kc], a, 0, 0, 0);
                    a = __builtin_amdgcn_mfma_f32_16x16x32_bf16(ah[kc], blf[nt][kc], a, 0, 0, 0);
                    a = __builtin_amdgcn_mfma_f32_16x16x32_bf16(al[kc], bhf[nt][kc], a, 0, 0, 0);
                }
            }
            acc[nt] = a;
        }

#pragma unroll
        for (int nt = 0; nt < 4; ++nt)
#pragma unroll
            for (int reg = 0; reg < 4; ++reg)
                sm.p.sF[(wv * 16 + q * 4 + reg) * 68 + nt * 16 + ml] = acc[nt][reg];

        float ps[4] = {0.f, 0.f, 0.f, 0.f}, pd[4] = {0.f, 0.f, 0.f, 0.f};
#pragma unroll
        for (int nt = 0; nt < 4; ++nt)
#pragma unroll
            for (int reg = 0; reg < 4; ++reg) {
                float tv = fast_tanh(acc[nt][reg]);
                ps[reg] += tv * aS[nt];
                pd[reg] += tv * aD[nt];
            }
#pragma unroll
        for (int msk = 1; msk < 16; msk <<= 1)
#pragma unroll
            for (int reg = 0; reg < 4; ++reg) {
                ps[reg] += __shfl_xor(ps[reg], msk, 64);
                pd[reg] += __shfl_xor(pd[reg], msk, 64);
            }
        if (ml == 0) {
#pragma unroll
            for (int reg = 0; reg < 4; ++reg) {
                int i = bh * NN + r0 + wv * 16 + q * 4 + reg;
                float sv = ps[reg], dv = pd[reg];
                stF(&sArr[i], sv);
                stF(&dArr[i], dv);
                stF(&rArr[i], __expf(-0.8f * sv));
            }
        }
        __syncthreads();
        {   // coalesced fp32 row write via IF$-routed 8B stores
            const int row = t >> 2, cs = (t & 3) * 16;
            const float* sp = &sm.p.sF[row * 68 + cs];
            float* dst = hpF + ((size_t)bh * NN + r0 + row) * 64 + cs;
#pragma unroll
            for (int g = 0; g < 8; ++g)
                stF2(dst + g * 2, sp[g * 2], sp[g * 2 + 1]);
        }
        // next-iter staging writes aHi/aLo (disjoint from sF); all aHi reads of
        // this tile completed before the mid-barrier -> no extra barrier needed.
    }
    bhsync(&flags[(0 * BH + bh) * 16], kb, 0x3A7C9E51u);

    // ================= P1: rank-by-count -> SDJ ==============================
    {
#pragma unroll
        for (int g = 0; g < 8; ++g) {
            int j = t + g * 256;
            unsigned m = mkey(ldF(&dArr[bh * NN + j]));
            sm.r.kp[j] = ((unsigned long long)m << 32) | (unsigned)(2047 - j);
        }
        __syncthreads();
        const int jj = kb * 128 + (t & 127);
        const unsigned long long K = sm.r.kp[jj];
        const int cbase = (t >> 7) * 1024;
        int cnt = 0;
#pragma unroll 8
        for (int c = cbase; c < cbase + 1024; c += 4) {
            u64x2 a = *(const u64x2*)&sm.r.kp[c];
            u64x2 bb = *(const u64x2*)&sm.r.kp[c + 2];
            cnt += (a.x > K) + (a.y > K) + (bb.x > K) + (bb.y > K);
        }
        sm.r.cnt2[t] = cnt;
        __syncthreads();
        if (t < 128) {
            int cc = sm.r.cnt2[t] + sm.r.cnt2[t + 128];
            unsigned m = (unsigned)(K >> 32);
            stU64(&SDJ[bh * NN + cc], ((unsigned long long)m << 32) | (unsigned)jj);
        }
    }
    bhsync(&flags[(1 * BH + bh) * 16], kb, 0x3A7C9E52u);

    // ================= P2: chunk totals (wave = one 32-rank chunk) ===========
    {
        const int c = kb * 4 + wv;
        float teh = 0.f, tel = 0.f, tehs = 0.f, tels = 0.f;
#pragma unroll 4
        for (int u = 0; u < 32; ++u) {
            unsigned long long K = ldU64(&SDJ[bh * NN + c * 32 + u]);
            int jj = (int)(K & 0xFFFFFFFFu);
            float d = unmkey((unsigned)(K >> 32));
            float eh = __expf(d), el = __expf(0.2f * d);
            float hv = ldF(&hpF[((size_t)bh * NN + jj) * 64 + lane]);
            teh += eh * hv; tel += el * hv; tehs += eh; tels += el;
        }
        stF(&Teh[(bh * 64 + c) * 64 + lane], teh);
        stF(&Tel[(bh * 64 + c) * 64 + lane], tel);
        if (lane == 0) { stF(&TehS[bh * 64 + c], tehs); stF(&TelS[bh * 64 + c], tels); }
    }
    bhsync(&flags[(2 * BH + bh) * 16], kb, 0x3A7C9E53u);

    // ========== P4: emit Pre/Suf tables (inline chunk-prefix, no cscan) ======
    {
        const int c = kb * 4 + wv;
        const size_t base = (size_t)bh * 2049;

        float run = 0.f, runs = 0.f;
        for (int cp = 0; cp < c; ++cp) {
            run  += ldF(&Teh[(bh * 64 + cp) * 64 + lane]);
            runs += ldF(&TehS[bh * 64 + cp]);
        }
#pragma unroll 4
        for (int u = 0; u < 32; ++u) {
            int x = c * 32 + u;
            unsigned long long K = ldU64(&SDJ[bh * NN + x]);
            int jj = (int)(K & 0xFFFFFFFFu);
            float d = unmkey((unsigned)(K >> 32));
            stF(&PreR[(base + x) * 64 + lane], run);
            if (lane == 0) stF(&PreS[base + x], runs);
            float eh = __expf(d);
            float hv = ldF(&hpF[((size_t)bh * NN + jj) * 64 + lane]);
            run += eh * hv; runs += eh;
        }
        if (c == 63) {
            stF(&PreR[(base + 2048) * 64 + lane], run);
            stF(&SufR[(base + 2048) * 64 + lane], 0.f);
            if (lane == 0) { stF(&PreS[base + 2048], runs); stF(&SufS[base + 2048], 0.f); }
        }

        float runb = 0.f, runbs = 0.f;
        for (int cp = c + 1; cp < 64; ++cp) {
            runb  += ldF(&Tel[(bh * 64 + cp) * 64 + lane]);
            runbs += ldF(&TelS[bh * 64 + cp]);
        }
#pragma unroll 4
        for (int u = 31; u >= 0; --u) {
            int x = c * 32 + u;
            unsigned long long K = ldU64(&SDJ[bh * NN + x]);
            int jj = (int)(K & 0xFFFFFFFFu);
            float d = unmkey((unsigned)(K >> 32));
            float el = __expf(0.2f * d);
            float hv = ldF(&hpF[((size_t)bh * NN + jj) * 64 + lane]);
            runb += el * hv; runbs += el;
            stF(&SufR[(base + x) * 64 + lane], runb);
            if (lane == 0) stF(&SufS[base + x], runbs);
        }
    }
    bhsync(&flags[(3 * BH + bh) * 16], kb, 0x3A7C9E54u);

    // ================= P5: per-row search + blend + normalize ================
    {
#pragma unroll
        for (int g = 0; g < 8; ++g)
            sm.o.sdM[t + g * 256] = (unsigned)(ldU64(&SDJ[bh * NN + t + g * 256]) >> 32);
        __syncthreads();
        const int i0 = kb * 128;
        if (t < 128) {   // cnt_i = #{ m_j >= m(thr_i) } over descending m array
            int i = i0 + t;
            unsigned mthr = mkey(-ldF(&sArr[bh * NN + i]));
            int lo = 0, hi = 2048;
            while (lo < hi) {
                int m = (lo + hi) >> 1;
                if (sm.o.sdM[m] >= mthr) lo = m + 1; else hi = m;
            }
            sm.o.cntS[t] = lo;
            sm.o.rS[t] = ldF(&rArr[bh * NN + i]);
        }
        __syncthreads();
        const size_t base = (size_t)bh * 2049;
        float biasv = LDIN(bias, lane, b16);
#pragma unroll 4
        for (int u = 0; u < 32; ++u) {
            int iu = wv * 32 + u;
            int cnt = sm.o.cntS[iu];
            float rr = sm.o.rS[iu];
            size_t ro = (base + cnt) * 64 + lane;
            float pre = ldF(&PreR[ro]), suf = ldF(&SufR[ro]);
            float pres = ldF(&PreS[base + cnt]), sufs = ldF(&SufS[base + cnt]);
            float val = (pre + rr * suf) / (pres + rr * sufs) + biasv;
            size_t oi = ((size_t)bh * NN + i0 + iu) * 64 + lane;
            if (b16) ((__hip_bfloat16*)out)[oi] = __float2bfloat16(val);
            else     ((float*)out)[oi] = val;
        }
    }
}

extern "C" void kernel_launch(void* const* d_in, const int* in_sizes, int n_in,
                              void* d_out, int out_size, void* d_ws, size_t ws_size,
                              hipStream_t stream) {
    const void* h    = d_in[0];
    // d_in[1] = adj (bool) — unused by reference
    const void* w    = d_in[2];
    const void* asrc = d_in[3];
    const void* adst = d_in[4];
    const void* bias = d_in[5];

    float* ws = (float*)d_ws;
    unsigned* flags = (unsigned*)ws;                      // 4 phases x 32 bh x 16 slots
    float*  hpF  = ws + 4096;                             // 32*2048*64 fp32
    float*  sArr = hpF + (size_t)BH * NN * FF;            // 65536
    float*  dArr = sArr + BH * NN;
    float*  rArr = dArr + BH * NN;
    unsigned long long* SDJ = (unsigned long long*)(rArr + BH * NN); // 65536 u64
    float*  Teh  = (float*)(SDJ + (size_t)BH * NN);       // 32*64*64
    float*  Tel  = Teh + BH * 64 * 64;
    float*  TehS = Tel + BH * 64 * 64;                    // 32*64
    float*  TelS = TehS + BH * 64;
    float*  PreR = TelS + BH * 64;                        // 32*2049*64
    float*  SufR = PreR + (size_t)BH * 2049 * FF;
    float*  PreS = SufR + (size_t)BH * 2049 * FF;         // 32*2049
    float*  SufS = PreS + (size_t)BH * 2049;

    void* outp = d_out;
    void* args[] = { (void*)&h, (void*)&w, (void*)&asrc, (void*)&adst,
                     (void*)&bias, (void*)&flags,
                     (void*)&hpF, (void*)&sArr, (void*)&dArr, (void*)&rArr,
                     (void*)&SDJ, (void*)&Teh, (void*)&Tel, (void*)&TehS,
                     (void*)&TelS, (void*)&PreR, (void*)&SufR, (void*)&PreS,
                     (void*)&SufS, (void*)&outp };
    hipError_t e = hipLaunchCooperativeKernel((void*)k_mega,
                                              dim3(BH * 16), dim3(256),
                                              args, 0, stream);
    if (e != hipSuccess) {
        (void)hipGetLastError();    // clear sticky error; fall back to plain launch
        k_mega<<<BH * 16, 256, 0, stream>>>(h, w, asrc, adst, bias, flags,
                                            hpF, sArr, dArr, rArr, SDJ,
                                            Teh, Tel, TehS, TelS,
                                            PreR, SufR, PreS, SufS, d_out);
    }
}

// Round 6
// 218.478 us; speedup vs baseline: 3.0328x; 1.2016x over previous
//
#include <hip/hip_runtime.h>
#include <hip/hip_bf16.h>

#define NN 2048
#define FF 64
#define NH 8
#define BDIM 4
#define BH 32        // BDIM*NH

typedef __attribute__((ext_vector_type(8))) short short8;
typedef __attribute__((ext_vector_type(4))) float floatx4;
typedef __attribute__((ext_vector_type(4))) unsigned uint4v;
typedef __attribute__((ext_vector_type(2))) unsigned long long u64x2;

__device__ __forceinline__ float LDIN(const void* p, size_t i, int b16) {
    return b16 ? __bfloat162float(((const __hip_bfloat16*)p)[i]) : ((const float*)p)[i];
}
__device__ __forceinline__ unsigned packhi(float f0, float f1) {
    return __builtin_amdgcn_perm(__float_as_uint(f1), __float_as_uint(f0), 0x07060302);
}
__device__ __forceinline__ float hitrunc(float x) {
    return __uint_as_float(__float_as_uint(x) & 0xFFFF0000u);
}
// XOR-swizzled LDS index (stride 64 shorts, 8-short groups). col must be 4-aligned.
__device__ __forceinline__ int SWZ(int row, int col) {
    return row * 64 + ((((col >> 3) ^ (row & 7)) << 3) | (col & 7));
}
__device__ __forceinline__ float fast_tanh(float v) {
    float ex = __expf(2.0f * v);
    return 1.0f - 2.0f * __builtin_amdgcn_rcpf(ex + 1.0f);
}
__device__ __forceinline__ int sniff_b16(const void* h) {
    unsigned word = ((const unsigned*)h)[threadIdx.x & 63];
    unsigned lowexp = (word >> 7) & 0xFFu;
    bool plaus = (lowexp >= 96u && lowexp <= 159u);
    unsigned long long m = __ballot(plaus);
    return (__popcll(m) >= 48) ? 1 : 0;
}
// monotone float->unsigned map: f0 < f1  <=>  mkey(f0) < mkey(f1)
__device__ __forceinline__ unsigned mkey(float f) {
    unsigned u = __float_as_uint(f);
    return (u & 0x80000000u) ? ~u : (u | 0x80000000u);
}
__device__ __forceinline__ float unmkey(unsigned m) {
    unsigned u = (m & 0x80000000u) ? (m - 0x80000000u) : ~m;
    return __uint_as_float(u);
}

// ---- Kernel 1: MFMA GEMM hp=h@w; fp32 hp rows + s/d/r per row ---------------
// grid 512 = 32 bh x 16 kb (two 64-row tiles each). 256 thr = 4 waves.
// w fragments loaded straight to registers (w is tiny and L2-hot).
__global__ __launch_bounds__(256) void k_proj(
    const void* __restrict__ h, const void* __restrict__ w,
    const void* __restrict__ asrc, const void* __restrict__ adst,
    float* __restrict__ hpF, float* __restrict__ sArr, float* __restrict__ dArr,
    float* __restrict__ rArr)
{
    const int t = threadIdx.x;
    const int bh = blockIdx.x >> 4, kb = blockIdx.x & 15;
    const int b = bh >> 3, hd = bh & 7;
    const int lane = t & 63, wv = t >> 6;
    const int ml = lane & 15, q = lane >> 4;

    __shared__ ushort aHi[4096];
    __shared__ ushort aLo[4096];
    __shared__ float  sF[64 * 68];
    __shared__ int sb16;
    if (t < 64) { int f = sniff_b16(h); if (t == 0) sb16 = f; }
    __syncthreads();
    const int b16 = sb16;

    short8 bhf[4][2], blf[4][2];
    if (b16) {
        const ushort* wp = (const ushort*)w + (size_t)hd * FF * FF;
#pragma unroll
        for (int nt = 0; nt < 4; ++nt)
#pragma unroll
            for (int kc = 0; kc < 2; ++kc) {
                ushort v[8];
#pragma unroll
                for (int j = 0; j < 8; ++j)
                    v[j] = wp[(kc * 32 + q * 8 + j) * FF + nt * 16 + ml];
                bhf[nt][kc] = *(short8*)v;
            }
    } else {
        const float* wp = (const float*)w + (size_t)hd * FF * FF;
#pragma unroll
        for (int nt = 0; nt < 4; ++nt)
#pragma unroll
            for (int kc = 0; kc < 2; ++kc) {
                float x[8];
#pragma unroll
                for (int j = 0; j < 8; ++j)
                    x[j] = wp[(kc * 32 + q * 8 + j) * FF + nt * 16 + ml];
                uint4v hv = { packhi(x[0], x[1]), packhi(x[2], x[3]),
                              packhi(x[4], x[5]), packhi(x[6], x[7]) };
                uint4v lv = { packhi(x[0] - hitrunc(x[0]), x[1] - hitrunc(x[1])),
                              packhi(x[2] - hitrunc(x[2]), x[3] - hitrunc(x[3])),
                              packhi(x[4] - hitrunc(x[4]), x[5] - hitrunc(x[5])),
                              packhi(x[6] - hitrunc(x[6]), x[7] - hitrunc(x[7])) };
                bhf[nt][kc] = __builtin_bit_cast(short8, hv);
                blf[nt][kc] = __builtin_bit_cast(short8, lv);
            }
    }

    float aS[4], aD[4];
#pragma unroll
    for (int nt = 0; nt < 4; ++nt) {
        aS[nt] = LDIN(asrc, hd * FF + nt * 16 + ml, b16);
        aD[nt] = LDIN(adst, hd * FF + nt * 16 + ml, b16);
    }

#pragma unroll 1
    for (int e = 0; e < 2; ++e) {
        const int r0 = (kb * 2 + e) * 64;
        if (b16) {
            const ushort* hsrc = (const ushort*)h + (size_t)(b * NN + r0) * FF;
#pragma unroll
            for (int g0 = 0; g0 < 2; ++g0) {
                int g = t + g0 * 256;
                int row = g >> 3, c8 = (g & 7) * 8;
                uint4v u = *(const uint4v*)(hsrc + row * FF + c8);
                *(uint4v*)&aHi[SWZ(row, c8)] = u;
            }
        } else {
            const float* hsrc = (const float*)h + (size_t)(b * NN + r0) * FF;
#pragma unroll
            for (int g0 = 0; g0 < 4; ++g0) {
                int g = t + g0 * 256;
                int row = g >> 4, c4 = (g & 15) * 4;
                floatx4 x = *(const floatx4*)(hsrc + row * FF + c4);
                uint2 hi2 = { packhi(x[0], x[1]), packhi(x[2], x[3]) };
                uint2 lo2 = { packhi(x[0] - hitrunc(x[0]), x[1] - hitrunc(x[1])),
                              packhi(x[2] - hitrunc(x[2]), x[3] - hitrunc(x[3])) };
                *(uint2*)&aHi[SWZ(row, c4)] = hi2;
                *(uint2*)&aLo[SWZ(row, c4)] = lo2;
            }
        }
        __syncthreads();

        short8 ah[2], al[2];
#pragma unroll
        for (int kc = 0; kc < 2; ++kc) {
            ah[kc] = *(const short8*)&aHi[SWZ(wv * 16 + ml, kc * 32 + q * 8)];
            if (!b16) al[kc] = *(const short8*)&aLo[SWZ(wv * 16 + ml, kc * 32 + q * 8)];
        }

        floatx4 acc[4];
#pragma unroll
        for (int nt = 0; nt < 4; ++nt) {
            floatx4 a = {0.f, 0.f, 0.f, 0.f};
            if (b16) {
#pragma unroll
                for (int kc = 0; kc < 2; ++kc)
                    a = __builtin_amdgcn_mfma_f32_16x16x32_bf16(ah[kc], bhf[nt][kc], a, 0, 0, 0);
            } else {
#pragma unroll
                for (int kc = 0; kc < 2; ++kc) {
                    a = __builtin_amdgcn_mfma_f32_16x16x32_bf16(ah[kc], bhf[nt][kc], a, 0, 0, 0);
                    a = __builtin_amdgcn_mfma_f32_16x16x32_bf16(ah[kc], blf[nt][kc], a, 0, 0, 0);
                    a = __builtin_amdgcn_mfma_f32_16x16x32_bf16(al[kc], bhf[nt][kc], a, 0, 0, 0);
                }
            }
            acc[nt] = a;
        }

#pragma unroll
        for (int nt = 0; nt < 4; ++nt)
#pragma unroll
            for (int reg = 0; reg < 4; ++reg)
                sF[(wv * 16 + q * 4 + reg) * 68 + nt * 16 + ml] = acc[nt][reg];

        float ps[4] = {0.f, 0.f, 0.f, 0.f}, pd[4] = {0.f, 0.f, 0.f, 0.f};
#pragma unroll
        for (int nt = 0; nt < 4; ++nt)
#pragma unroll
            for (int reg = 0; reg < 4; ++reg) {
                float tv = fast_tanh(acc[nt][reg]);
                ps[reg] += tv * aS[nt];
                pd[reg] += tv * aD[nt];
            }
#pragma unroll
        for (int msk = 1; msk < 16; msk <<= 1)
#pragma unroll
            for (int reg = 0; reg < 4; ++reg) {
                ps[reg] += __shfl_xor(ps[reg], msk, 64);
                pd[reg] += __shfl_xor(pd[reg], msk, 64);
            }
        if (ml == 0) {
#pragma unroll
            for (int reg = 0; reg < 4; ++reg) {
                int i = bh * NN + r0 + wv * 16 + q * 4 + reg;
                float sv = ps[reg], dv = pd[reg];
                sArr[i] = sv;
                dArr[i] = dv;
                rArr[i] = __expf(-0.8f * sv);
            }
        }
        __syncthreads();
        {   // coalesced fp32 row write: each thread stores 16 floats of one row
            const int row = t >> 2, cs = (t & 3) * 16;
            const float* sp = &sF[row * 68 + cs];
            float* dst = hpF + ((size_t)bh * NN + r0 + row) * 64 + cs;
            *(floatx4*)(dst)      = *(const floatx4*)(sp);
            *(floatx4*)(dst + 4)  = *(const floatx4*)(sp + 4);
            *(floatx4*)(dst + 8)  = *(const floatx4*)(sp + 8);
            *(floatx4*)(dst + 12) = *(const floatx4*)(sp + 12);
        }
        // next-iter staging writes aHi/aLo (disjoint from sF); a __syncthreads
        // separates this tile's aHi reads from the next tile's writes.
        __syncthreads();
    }
}

// ---- Kernel 2: rank-by-count (zero inner barriers) --------------------------
// grid 256 = 32 bh x 8 slabs; 256 thr. rank_j = #{K' > K_j} over packed keys
// (descending d, index tie-break). Scatters SDJ[rank] = (mkey(d)<<32)|j.
__global__ __launch_bounds__(256) void k_rank(
    const float* __restrict__ dArr, unsigned long long* __restrict__ SDJ)
{
    const int bh = blockIdx.x >> 3, slab = blockIdx.x & 7, t = threadIdx.x;
    __shared__ __align__(16) unsigned long long kp[2048];
#pragma unroll
    for (int g = 0; g < 8; ++g) {
        int j = t + g * 256;
        unsigned m = mkey(dArr[bh * NN + j]);
        kp[j] = ((unsigned long long)m << 32) | (unsigned)(2047 - j);
    }
    __syncthreads();
    const int j = slab * 256 + t;
    const unsigned long long K = kp[j];
    int cnt = 0;
#pragma unroll 8
    for (int c = 0; c < 2048; c += 4) {
        u64x2 a = *(const u64x2*)&kp[c];
        u64x2 b = *(const u64x2*)&kp[c + 2];
        cnt += (a.x > K) + (a.y > K) + (b.x > K) + (b.y > K);
    }
    unsigned m = (unsigned)(K >> 32);
    SDJ[bh * NN + cnt] = ((unsigned long long)m << 32) | (unsigned)j;
}

// ---- Kernel 3: per-chunk totals + per-row threshold count -------------------
// grid 512 = 32 bh x 16; 256 thr = 4 waves (wave = one 32-rank chunk).
// Also: threads 0..127 binary-search cnt_i for rows kb*128..+127.
__global__ __launch_bounds__(256) void k_chunk2(
    const unsigned long long* __restrict__ SDJ, const float* __restrict__ hpF,
    const float* __restrict__ sArr,
    float* __restrict__ Teh, float* __restrict__ Tel,
    float* __restrict__ TehS, float* __restrict__ TelS,
    int* __restrict__ rowCnt)
{
    const int bh = blockIdx.x >> 4, kb = blockIdx.x & 15;
    const int t = threadIdx.x, lane = t & 63, wv = t >> 6;
    __shared__ unsigned sdM[2048];
#pragma unroll
    for (int g = 0; g < 8; ++g)
        sdM[t + g * 256] = (unsigned)(SDJ[bh * NN + t + g * 256] >> 32);

    const int c = kb * 4 + wv;
    float teh = 0.f, tel = 0.f, tehs = 0.f, tels = 0.f;
#pragma unroll 4
    for (int u = 0; u < 32; ++u) {
        unsigned long long K = SDJ[bh * NN + c * 32 + u];
        int jj = (int)(K & 0xFFFFFFFFu);
        float d = unmkey((unsigned)(K >> 32));
        float eh = __expf(d), el = __expf(0.2f * d);
        float hv = hpF[((size_t)bh * NN + jj) * 64 + lane];
        teh += eh * hv; tel += el * hv; tehs += eh; tels += el;
    }
    Teh[(bh * 64 + c) * 64 + lane] = teh;
    Tel[(bh * 64 + c) * 64 + lane] = tel;
    if (lane == 0) { TehS[bh * 64 + c] = tehs; TelS[bh * 64 + c] = tels; }

    __syncthreads();
    if (t < 128) {   // cnt_i = #{ m_j >= m(-s_i) } over descending m array
        int i = kb * 128 + t;
        unsigned mthr = mkey(-sArr[bh * NN + i]);
        int lo = 0, hi = 2048;
        while (lo < hi) {
            int m = (lo + hi) >> 1;
            if (sdM[m] >= mthr) lo = m + 1; else hi = m;
        }
        rowCnt[bh * NN + i] = lo;
    }
}

// ---- Kernel 4: fused emit+out sweep (no Pre/Suf tables) ---------------------
// grid 512 = 32 bh x 16; 256 thr = 4 waves; wave = chunk c = kb*4+wv.
// Per wave: chunk prefix/suffix from totals; backward walk stores 32-step
// inclusive suffix in LDS; forward walk emits finished rows whose cnt == x
// (rows found by scanning rowCnt once into a per-wave LDS list).
__global__ __launch_bounds__(256) void k_sweep(
    const void* __restrict__ h,
    const unsigned long long* __restrict__ SDJ, const float* __restrict__ hpF,
    const int* __restrict__ rowCnt, const float* __restrict__ rArr,
    const float* __restrict__ Teh, const float* __restrict__ Tel,
    const float* __restrict__ TehS, const float* __restrict__ TelS,
    const void* __restrict__ bias, void* __restrict__ out)
{
    const int bh = blockIdx.x >> 4, kb = blockIdx.x & 15;
    const int t = threadIdx.x, lane = t & 63, wv = t >> 6;
    const int c = kb * 4 + wv;

    __shared__ float sufV[4][33][64];     // 33.8 KB: inclusive el-suffix history
    __shared__ float sufSs[4][33];
    __shared__ unsigned listW[4][512];    // 8 KB: per-wave (cnt,i) lists
    __shared__ int cntW[4];
    __shared__ int sb16;
    if (t < 64) { int f = sniff_b16(h); if (t == 0) sb16 = f; }
    if (lane == 0) cntW[wv] = 0;
    __syncthreads();
    const int b16 = sb16;

    // chunk-prefix (eh) and chunk-suffix (el) over chunk totals (same order
    // as the proven R2 scans: prefix ascending, suffix descending)
    float preV = 0.f, preS = 0.f;
    for (int cp = 0; cp < c; ++cp) {
        preV += Teh[(bh * 64 + cp) * 64 + lane];
        preS += TehS[bh * 64 + cp];
    }
    float sufT = 0.f, sufTS = 0.f;
    for (int cp = 63; cp > c; --cp) {
        sufT += Tel[(bh * 64 + cp) * 64 + lane];
        sufTS += TelS[bh * 64 + cp];
    }

    // backward within-chunk walk: inclusive suffix at each u
    if (c == 63) { sufV[wv][32][lane] = 0.f; if (lane == 0) sufSs[wv][32] = 0.f; }
    {
        float run = sufT, runs = sufTS;
#pragma unroll 4
        for (int u = 31; u >= 0; --u) {
            int x = c * 32 + u;
            unsigned long long K = SDJ[bh * NN + x];
            int jj = (int)(K & 0xFFFFFFFFu);
            float d = unmkey((unsigned)(K >> 32));
            float el = __expf(0.2f * d);
            float hv = hpF[((size_t)bh * NN + jj) * 64 + lane];
            run += el * hv; runs += el;
            sufV[wv][u][lane] = run;
            if (lane == 0) sufSs[wv][u] = runs;
        }
    }

    // build the per-wave row list: rows whose cnt falls in this chunk
    const int xlo = c * 32, xhi = (c == 63) ? (2048 + 1) : (c * 32 + 32);
    for (int g = 0; g < 32; ++g) {
        int i = g * 64 + lane;
        int cn = rowCnt[bh * NN + i];
        if (cn >= xlo && cn < xhi) {
            int idx = atomicAdd(&cntW[wv], 1);
            if (idx < 512) listW[wv][idx] = ((unsigned)cn << 11) | (unsigned)i;
        }
    }
    const int lenRaw = cntW[wv];
    const int len = lenRaw < 512 ? lenRaw : 512;
    const bool slow = (lenRaw > 512);    // ~impossible; correctness fallback

    const size_t obase = (size_t)bh * NN;
    const float biasv = LDIN(bias, lane, b16);

    // forward walk: emit rows at x BEFORE adding rank x's contribution
    const int uMax = (c == 63) ? 33 : 32;
    for (int u = 0; u < uMax; ++u) {
        const int x = c * 32 + u;
        if (!slow) {
            for (int s0 = 0; s0 < len; s0 += 64) {
                int sl = s0 + lane;
                unsigned e = (sl < len) ? listW[wv][sl] : 0xFFFFFFFFu;
                bool m0 = (sl < len) && ((int)(e >> 11) == x);
                unsigned long long mask = __ballot(m0);
                while (mask) {
                    int l = __ffsll((long long)mask) - 1; mask &= mask - 1;
                    unsigned ee = __shfl(e, l);
                    int i = (int)(ee & 2047u);
                    float rr = rArr[obase + i];
                    float val = (preV + rr * sufV[wv][u][lane])
                              / (preS + rr * sufSs[wv][u]) + biasv;
                    size_t oi = (obase + i) * 64 + lane;
                    if (b16) ((__hip_bfloat16*)out)[oi] = __float2bfloat16(val);
                    else     ((float*)out)[oi] = val;
                }
            }
        } else {
            for (int g = 0; g < 32; ++g) {
                int i0 = g * 64 + lane;
                int cn = rowCnt[bh * NN + i0];
                unsigned long long mask = __ballot(cn == x);
                while (mask) {
                    int l = __ffsll((long long)mask) - 1; mask &= mask - 1;
                    int i = g * 64 + l;
                    float rr = rArr[obase + i];
                    float val = (preV + rr * sufV[wv][u][lane])
                              / (preS + rr * sufSs[wv][u]) + biasv;
                    size_t oi = (obase + i) * 64 + lane;
                    if (b16) ((__hip_bfloat16*)out)[oi] = __float2bfloat16(val);
                    else     ((float*)out)[oi] = val;
                }
            }
        }
        if (u < 32) {
            unsigned long long K = SDJ[bh * NN + x];
            int jj = (int)(K & 0xFFFFFFFFu);
            float d = unmkey((unsigned)(K >> 32));
            float eh = __expf(d);
            float hv = hpF[((size_t)bh * NN + jj) * 64 + lane];
            preV += eh * hv; preS += eh;
        }
    }
}

extern "C" void kernel_launch(void* const* d_in, const int* in_sizes, int n_in,
                              void* d_out, int out_size, void* d_ws, size_t ws_size,
                              hipStream_t stream) {
    const void* h    = d_in[0];
    // d_in[1] = adj (bool) — unused by reference
    const void* w    = d_in[2];
    const void* asrc = d_in[3];
    const void* adst = d_in[4];
    const void* bias = d_in[5];

    float* ws = (float*)d_ws;
    float*  hpF  = ws;                                    // 32*2048*64 fp32 (16 MB)
    float*  sArr = hpF + (size_t)BH * NN * FF;            // 65536
    float*  dArr = sArr + BH * NN;
    float*  rArr = dArr + BH * NN;
    unsigned long long* SDJ = (unsigned long long*)(rArr + BH * NN); // 65536 u64
    float*  Teh  = (float*)(SDJ + (size_t)BH * NN);       // 32*64*64
    float*  Tel  = Teh + BH * 64 * 64;
    float*  TehS = Tel + BH * 64 * 64;                    // 32*64
    float*  TelS = TehS + BH * 64;
    int*    rowCnt = (int*)(TelS + BH * 64);              // 32*2048 int

    k_proj<<<BH * 16, 256, 0, stream>>>(h, w, asrc, adst, hpF, sArr, dArr, rArr);
    k_rank<<<BH * 8, 256, 0, stream>>>(dArr, SDJ);
    k_chunk2<<<BH * 16, 256, 0, stream>>>(SDJ, hpF, sArr, Teh, Tel, TehS, TelS, rowCnt);
    k_sweep<<<BH * 16, 256, 0, stream>>>(h, SDJ, hpF, rowCnt, rArr,
                                         Teh, Tel, TehS, TelS, bias, d_out);
}